// Round 18
// baseline (158.507 us; speedup 1.0000x reference)
//
#include <hip/hip_runtime.h>

#define BB 4
#define QQ 256
#define VV 2048
#define HH 512
#define UU 128

// tanh arg scale folded into projections: C2E = 2*log2(e); exp(x)=exp2(x*LOG2E)
#define C2E   2.8853900817779268f
#define LOG2E 1.4426950408889634f

typedef float f32x2v __attribute__((ext_vector_type(2)));

__device__ __forceinline__ void fma4(float4& a, float s, const float4& w) {
    a.x = fmaf(s, w.x, a.x);
    a.y = fmaf(s, w.y, a.y);
    a.z = fmaf(s, w.z, a.z);
    a.w = fmaf(s, w.w, a.w);
}
__device__ __forceinline__ f32x2v bc2(float x) { return (f32x2v){x, x}; }

// ---------------------------------------------------------------------------
// Projection GEMM -> EXPONENTIATED, INTERLEAVED transposed output.
// (R12 version, known-good, ~13us by R17 budget calibration.)
// ---------------------------------------------------------------------------
__global__ __launch_bounds__(256) void proj_kernel(const float* __restrict__ queries,
                                                   const float* __restrict__ values,
                                                   const float* __restrict__ w1,
                                                   const float* __restrict__ w2,
                                                   float* __restrict__ pqI,
                                                   float* __restrict__ pvI,
                                                   float* __restrict__ denom) {
    __shared__ float smem[32 * 36 + 32 * 128];   // As[32][36] | Ws[32*128]; Ls aliases
    float (*As)[36] = (float(*)[36])smem;        // [k][row], stride 36 (16B-aligned rows)
    float* Ws = smem + 32 * 36;                  // [k][u]
    float (*Ls)[36] = (float(*)[36])smem;        // [u][row], epilogue (after barrier)

    const int bid = blockIdx.x;
    const int tid = threadIdx.x;
    if (bid == 0) *(float4*)&denom[tid * 4] = make_float4(0.f, 0.f, 0.f, 0.f);

    const bool isv = (bid < 256);
    const float* A; const float* W; int b, r0, ROWS; float* Ob;
    if (isv) {                             // values: 8192 rows, 64 blocks/batch
        b = bid >> 6; r0 = (bid & 63) * 32;
        A = values + ((size_t)(b * VV + r0)) * HH;  W = w2;
        Ob = pvI + (size_t)b * UU * VV;  ROWS = VV;
    } else {                               // queries: 1024 rows, 8 blocks/batch
        const int q = bid - 256;
        b = q >> 3; r0 = (q & 7) * 32;
        A = queries + ((size_t)(b * QQ + r0)) * HH; W = w1;
        Ob = pqI + (size_t)b * UU * QQ;  ROWS = QQ;
    }

    const int tx = tid & 31;         // u-group: u = tx*4 .. tx*4+3
    const int ty = tid >> 5;         // row-quad: rows 4ty .. 4ty+3
    float4 acc[4];
#pragma unroll
    for (int j = 0; j < 4; j++) acc[j] = make_float4(0.f, 0.f, 0.f, 0.f);

    for (int k0 = 0; k0 < HH; k0 += 32) {
        {   // A tile: 32 rows x 32 k, transposed store; one float4 per thread
            const int r = tid >> 3, kk4 = (tid & 7) * 4;
            const float4 a = *(const float4*)&A[(size_t)r * HH + k0 + kk4];
            As[kk4 + 0][r] = a.x; As[kk4 + 1][r] = a.y;
            As[kk4 + 2][r] = a.z; As[kk4 + 3][r] = a.w;
        }
#pragma unroll
        for (int t = 0; t < 4; t++) {  // W tile: 32 k x 128 u
            const int f = tid + t * 256;
            const int kk = f >> 5, u4 = (f & 31) * 4;
            *(float4*)&Ws[kk * 128 + u4] = *(const float4*)&W[(size_t)(k0 + kk) * UU + u4];
        }
        __syncthreads();
#pragma unroll
        for (int kk = 0; kk < 32; kk++) {
            const float4 a = *(const float4*)&As[kk][ty * 4];       // 4 rows
            const float4 w = *(const float4*)&Ws[kk * 128 + tx * 4];
            fma4(acc[0], a.x, w);
            fma4(acc[1], a.y, w);
            fma4(acc[2], a.z, w);
            fma4(acc[3], a.w, w);
        }
        __syncthreads();
    }
    // epilogue: exp2 + transpose via Ls (aliases As/Ws — barrier passed above)
#pragma unroll
    for (int j = 0; j < 4; j++) {
        const float aa[4] = {acc[j].x, acc[j].y, acc[j].z, acc[j].w};
#pragma unroll
        for (int i = 0; i < 4; i++)
            Ls[tx * 4 + i][ty * 4 + j] = __builtin_amdgcn_exp2f(aa[i] * C2E);
    }
    __syncthreads();
#pragma unroll
    for (int t = 0; t < 4; t++) {    // 1024 float4 chunks: (g = idx>>5, r = idx&31)
        const int idx = tid + t * 256;
        const int g = idx >> 5, r = idx & 31;
        float4 o;
        o.x = Ls[4 * g + 0][r]; o.y = Ls[4 * g + 1][r];
        o.z = Ls[4 * g + 2][r]; o.w = Ls[4 * g + 3][r];
        *(float4*)&Ob[((size_t)g * ROWS + r0 + r) * 4] = o;
    }
}

// ---------------------------------------------------------------------------
// R25 fused: R24 (packed Phase A, -4.9us confirmed) + PACKED Phase B.
// Phase B's 4096 scalar FMAs/thread (~13.7us VALU busy by the calibrated
// instr model) halve to 2048 v_pk_fma_f32. Same fma ops, same order ->
// bit-identical output. Only the B inner loop + oacc representation change.
// ---------------------------------------------------------------------------
__global__ __launch_bounds__(1024, 4) void fused_kernel(const float* __restrict__ pqI,
                                                        const float* __restrict__ pvI,
                                                        const float* __restrict__ vvec,
                                                        const float* __restrict__ values,
                                                        float* __restrict__ slab,
                                                        float* __restrict__ denom) {
    __shared__ float att[512][20];        // [v][q] padded; persists A->B
    __shared__ float scratch[24 * 512];   // 48KB: A-combine cbuf [16][512] / B-scratch [24][512]
    __shared__ float wred[8][8];
    __shared__ float eqs[32 * 64];        // 8KB: Eq tile [G][4 u][16 q]
    const int tid = threadIdx.x;
    const int bid = blockIdx.x;
    const int vs = bid & 3, qb = (bid >> 2) & 15, b = bid >> 6;
    const int qbase = qb * 16, vbase = vs * 512;

    // ---- Phase A ----
    const int vgrp = tid & 127;           // v = vbase + vgrp + k*128, k=0..3
    const int qq = (tid >> 7) & 3;        // wave-uniform q-quad (4 q)
    const int uh = tid >> 9;              // wave-uniform u-half

    const float* pq4 = pqI + (size_t)b * UU * QQ + (size_t)qbase * 4;  // Eq block (16q x 4u per G)

    // stage Eq tile TRANSPOSED: eqs[G][u][q]; 512 coalesced b128 loads
    if (tid < 512) {
        const int G = tid >> 4, q = tid & 15;
        const float4 lq = *(const float4*)&pq4[(size_t)G * QQ * 4 + q * 4];
        eqs[(G * 4 + 0) * 16 + q] = lq.x;
        eqs[(G * 4 + 1) * 16 + q] = lq.y;
        eqs[(G * 4 + 2) * 16 + q] = lq.z;
        eqs[(G * 4 + 3) * 16 + q] = lq.w;
    }

    float vsum = 0.0f;
#pragma unroll
    for (int u4 = 0; u4 < UU; u4 += 4) {
        const float4 t = *(const float4*)&vvec[u4];
        vsum += t.x + t.y + t.z + t.w;
    }

    const float* pvb = pvI + (size_t)b * UU * VV + (size_t)(vbase + vgrp) * 4;  // Ev streams

    f32x2v acc[4][2];                     // [k][p]; [0]=even q, [1]=odd q
#pragma unroll
    for (int k = 0; k < 4; k++) { acc[k][0] = bc2(0.f); acc[k][1] = bc2(0.f); }

    const int G0 = uh * 16;
    float4 ev[4], evn[4];
#pragma unroll
    for (int k = 0; k < 4; k++)           // prefetch g=0, 4 streams
        ev[k] = *(const float4*)&pvb[(size_t)G0 * VV * 4 + k * 128 * 4];
    __syncthreads();   // Eq staged

    const f32x2v one = bc2(1.f);
    for (int g = 0; g < 16; g++) {
        const int G = G0 + g;
        // e-tile: 4 uniform b128 reads (one per u), 4 q's each -> 2 q-pairs
        f32x2v ep[4][2];
#pragma unroll
        for (int u = 0; u < 4; u++) {
            const float4 equ = *(const float4*)&eqs[(G * 4 + u) * 16 + qq * 4];
            ep[u][0] = (f32x2v){equ.x, equ.y};   // q = qq*4+0, qq*4+1
            ep[u][1] = (f32x2v){equ.z, equ.w};   // q = qq*4+2, qq*4+3
        }
        if (g < 15) {
#pragma unroll
            for (int k = 0; k < 4; k++)
                evn[k] = *(const float4*)&pvb[(size_t)(G + 1) * VV * 4 + k * 128 * 4];
        }
        const float4 wq = *(const float4*)&vvec[G * 4];
        const f32x2v w0p = bc2(2.f * wq.x), w1p = bc2(2.f * wq.y);
        const f32x2v w2p = bc2(2.f * wq.z), w3p = bc2(2.f * wq.w);
#pragma unroll
        for (int k = 0; k < 4; k++) {
            const f32x2v evx = bc2(ev[k].x), evy = bc2(ev[k].y);
            const f32x2v evz = bc2(ev[k].z), evw = bc2(ev[k].w);
#pragma unroll
            for (int p = 0; p < 2; p++) {
                const f32x2v a1 = __builtin_elementwise_fma(ep[0][p], evx, one);
                const f32x2v b1 = __builtin_elementwise_fma(ep[1][p], evy, one);
                const f32x2v c1 = __builtin_elementwise_fma(ep[2][p], evz, one);
                const f32x2v d1 = __builtin_elementwise_fma(ep[3][p], evw, one);
                const f32x2v pab = a1 * b1, pcd = c1 * d1;
                const f32x2v nab = __builtin_elementwise_fma(a1, w1p, b1 * w0p);
                const f32x2v ncd = __builtin_elementwise_fma(c1, w3p, d1 * w2p);
                const f32x2v num = __builtin_elementwise_fma(nab, pcd, ncd * pab);
                const f32x2v den = pab * pcd;
                const f32x2v r = {__builtin_amdgcn_rcpf(den[0]), __builtin_amdgcn_rcpf(den[1])};
                acc[k][p] = __builtin_elementwise_fma(num, r, acc[k][p]);
            }
        }
#pragma unroll
        for (int k = 0; k < 4; k++) ev[k] = evn[k];
    }

    // combine u-halves via cbuf[q][v] (q-major, lane-consecutive b32)
    float* cb = scratch;   // [16 q][512 v]
    if (uh == 1) {
#pragma unroll
        for (int p = 0; p < 2; p++)
#pragma unroll
            for (int k = 0; k < 4; k++) {
                cb[(qq * 4 + 2 * p + 0) * 512 + vgrp + k * 128] = acc[k][p][0];
                cb[(qq * 4 + 2 * p + 1) * 512 + vgrp + k * 128] = acc[k][p][1];
            }
    }
    __syncthreads();
    if (uh == 0) {
#pragma unroll
        for (int p = 0; p < 2; p++)
#pragma unroll
            for (int k = 0; k < 4; k++) {
                const float hx = cb[(qq * 4 + 2 * p + 0) * 512 + vgrp + k * 128];
                const float hy = cb[(qq * 4 + 2 * p + 1) * 512 + vgrp + k * 128];
                float2 e;
                e.x = __builtin_amdgcn_exp2f((vsum - (acc[k][p][0] + hx)) * LOG2E);
                e.y = __builtin_amdgcn_exp2f((vsum - (acc[k][p][1] + hy)) * LOG2E);
                *(float2*)&att[vgrp + k * 128][qq * 4 + 2 * p] = e;
                acc[k][p] = (f32x2v){e.x, e.y};
            }
        // denom partials: combine the 4 v-offsets, then butterfly over 64 lanes
        float2 s[2];
#pragma unroll
        for (int p = 0; p < 2; p++) {
            s[p].x = acc[0][p][0] + acc[1][p][0] + acc[2][p][0] + acc[3][p][0];
            s[p].y = acc[0][p][1] + acc[1][p][1] + acc[2][p][1] + acc[3][p][1];
        }
#pragma unroll
        for (int off = 1; off < 64; off <<= 1) {
#pragma unroll
            for (int p = 0; p < 2; p++) {
                s[p].x += __shfl_xor(s[p].x, off, 64);
                s[p].y += __shfl_xor(s[p].y, off, 64);
            }
        }
        if ((tid & 63) == 0) {
            const int w = tid >> 6;   // 0..7 (uh=0): waves (2m,2m+1) share qq=m
#pragma unroll
            for (int p = 0; p < 2; p++) {
                wred[w][2 * p + 0] = s[p].x;
                wred[w][2 * p + 1] = s[p].y;
            }
        }
    }
    __syncthreads();
    if (tid < 16) {
        const int qq2 = tid >> 2, j = tid & 3;   // q = qq2*4 + j
        atomicAdd(&denom[b * QQ + qbase + tid],
                  wred[2 * qq2][j] + wred[2 * qq2 + 1][j]);
    }

    // ---- Phase B: (qh: 8 q, vh: 4 v-quarters of 128) across 8 half-waves ----
    // PACKED: oacc as f32x2v pairs; 16 v_pk_fma per vv (was 32 scalar).
    const int hg = tid & 127, sel = tid >> 7;       // sel wave-uniform
    const int qhb = sel & 1, vh = sel >> 1;         // vh 0..3
    const int h0 = hg * 4;
    const float* vp = values + ((size_t)(b * VV + vbase + vh * 128)) * HH + h0;

    f32x2v oacc[8][2];
#pragma unroll
    for (int j = 0; j < 8; j++) { oacc[j][0] = bc2(0.f); oacc[j][1] = bc2(0.f); }

#pragma unroll 2
    for (int vv = 0; vv < 128; vv++) {
        const float4 w = *(const float4*)&vp[(size_t)vv * HH];
        const f32x2v wl = (f32x2v){w.x, w.y}, wh = (f32x2v){w.z, w.w};
        const float4 a0 = *(const float4*)&att[vh * 128 + vv][qhb * 8 + 0];  // broadcast
        const float4 a1 = *(const float4*)&att[vh * 128 + vv][qhb * 8 + 4];
        const float aa[8] = {a0.x, a0.y, a0.z, a0.w, a1.x, a1.y, a1.z, a1.w};
#pragma unroll
        for (int j = 0; j < 8; j++) {
            const f32x2v s = bc2(aa[j]);
            oacc[j][0] = __builtin_elementwise_fma(s, wl, oacc[j][0]);
            oacc[j][1] = __builtin_elementwise_fma(s, wh, oacc[j][1]);
        }
    }

    // epilogue: 2 rounds over qh; vh 1..3 stage to 3 LDS buffers, vh 0 sums+stores
    float (*scr)[512] = (float(*)[512])scratch;   // 24 rows x 512
    for (int rr = 0; rr < 2; rr++) {
        __syncthreads();
        if (qhb == rr && vh > 0) {
#pragma unroll
            for (int j = 0; j < 8; j++) {
                float4 o;
                o.x = oacc[j][0][0]; o.y = oacc[j][0][1];
                o.z = oacc[j][1][0]; o.w = oacc[j][1][1];
                *(float4*)&scr[(vh - 1) * 8 + j][h0] = o;
            }
        }
        __syncthreads();
        if (qhb == rr && vh == 0) {
            float* sp = slab + (size_t)vs * (BB * QQ * HH);
#pragma unroll
            for (int j = 0; j < 8; j++) {
                const float4 p0 = *(const float4*)&scr[0 * 8 + j][h0];
                const float4 p1 = *(const float4*)&scr[1 * 8 + j][h0];
                const float4 p2 = *(const float4*)&scr[2 * 8 + j][h0];
                float4 o;
                o.x = oacc[j][0][0] + p0.x + p1.x + p2.x;
                o.y = oacc[j][0][1] + p0.y + p1.y + p2.y;
                o.z = oacc[j][1][0] + p0.z + p1.z + p2.z;
                o.w = oacc[j][1][1] + p0.w + p1.w + p2.w;
                *(float4*)&sp[((size_t)(b * QQ + qbase + rr * 8 + j)) * HH + h0] = o;
            }
        }
    }
}

// ---------------------------------------------------------------------------
// out = (sum of 4 slabs) * rcp(denom[row]). 131072 float4s, grid 512.
// ---------------------------------------------------------------------------
__global__ __launch_bounds__(256) void reduce_kernel(const float* __restrict__ slab,
                                                     const float* __restrict__ denom,
                                                     float* __restrict__ out) {
    const int i = blockIdx.x * 256 + threadIdx.x;    // float4 index
    const float r = __builtin_amdgcn_rcpf(denom[i >> 7]);
    const float4* s4 = (const float4*)slab;
    float4 s = s4[i];
#pragma unroll
    for (int k = 1; k < 4; k++) {
        const float4 p = s4[(size_t)k * (BB * QQ * HH / 4) + i];
        s.x += p.x; s.y += p.y; s.z += p.z; s.w += p.w;
    }
    s.x *= r; s.y *= r; s.z *= r; s.w *= r;
    ((float4*)out)[i] = s;
}

// ---------------------------------------------------------------------------
extern "C" void kernel_launch(void* const* d_in, const int* in_sizes, int n_in,
                              void* d_out, int out_size, void* d_ws, size_t ws_size,
                              hipStream_t stream) {
    const float* queries = (const float*)d_in[0];  // [B,Q,H]
    const float* values  = (const float*)d_in[1];  // [B,V,H]
    const float* w1      = (const float*)d_in[2];  // [H,U]
    const float* w2      = (const float*)d_in[3];  // [H,U]
    const float* vvec    = (const float*)d_in[4];  // [U]
    float* out = (float*)d_out;

    // ws (floats): pqI[131072] | pvI[1048576] | denom[1024] | slab[4*524288]
    float* ws    = (float*)d_ws;
    float* pqI   = ws;
    float* pvI   = pqI + BB * UU * QQ;
    float* denom = pvI + (size_t)BB * UU * VV;
    float* slab  = denom + BB * QQ;

    proj_kernel<<<256 + 32, 256, 0, stream>>>(queries, values, w1, w2, pqI, pvI, denom);
    fused_kernel<<<BB * (QQ / 16) * (VV / 512), 1024, 0, stream>>>(pqI, pvI, vvec, values, slab, denom);
    reduce_kernel<<<(BB * QQ * HH) / 4 / 256, 256, 0, stream>>>(slab, denom, out);
}